// Round 8
// baseline (384.629 us; speedup 1.0000x reference)
//
#include <hip/hip_runtime.h>
#include <math.h>

#define TPB 192
#define SPB 2   // samples per block, processed sequentially (dispatch-rate test)

// ---- LDS layout (float offsets), lifetime-overlaid; identical to R6. ----
// x   [0,784)   c1 [784,1840) [8][11][12]   f [1840,1930)   h [1932,1964)
// y   [784,2264) [10][12][12] ic-stride 148   k [2264,2304)
// P2  [2304,3604) [20][65]
// p3 [0,320) pf [320,420) a1 [420,470) z [472,482)  (over dead x)
#define OX    0
#define OC1   784
#define OF    1840
#define OH    1932
#define OY    784
#define YIC   148
#define OK2   2264
#define OP2   2304
#define OP3   0
#define OPF   320
#define OA1   420
#define OZ    472
#define SM_TOT 3604   // 14416 B

// R8: dispatch-rate test. R7 (2 samples CONCURRENT, 6-wave blocks) tanked
// occupancy 59->33 — fat-block geometry refuted. But a mechanism consistent
// with ALL rounds' nulls (R0/R1/R2 occupancy knobs, R7 inversion): per-CU
// block refill rate ~6.9us vs ~7us block runtime -> residency is refill-
// limited, invariant to static caps. This round: same 192-thread blocks,
// each runs 2 samples SEQUENTIALLY (grid 4096) — halves dispatch pressure
// with zero change to per-sample code, barrier width, or LDS footprint.
// Body is byte-identical to R6 (scalar weight loads; no forced rolling).
__global__ __launch_bounds__(TPB) void fused_forward(
    const float* __restrict__ x,
    const float* __restrict__ kf_w1, const float* __restrict__ kf_b1,
    const float* __restrict__ kf_w2, const float* __restrict__ kf_b2,
    const float* __restrict__ kf_fc1_w, const float* __restrict__ kf_fc1_b,
    const float* __restrict__ kf_fc2_w, const float* __restrict__ kf_fc2_b,
    const float* __restrict__ conv2_w, const float* __restrict__ conv2_b,
    const float* __restrict__ fc1_w, const float* __restrict__ fc1_b,
    const float* __restrict__ fc2_w, const float* __restrict__ fc2_b,
    float* __restrict__ out)
{
    __shared__ __align__(16) float sm[SM_TOT];
    const int tid = threadIdx.x;

    for (int rep = 0; rep < SPB; ++rep) {
        const int n = blockIdx.x * SPB + rep;
        if (rep) __syncthreads();   // arena reuse: tail reads p3/pf/a1/z over x

        // ---- stage 0: stage x into LDS (float4) ----
        {
            const float4* xg = (const float4*)(x + (long long)n * 784);
            float4* d = (float4*)&sm[OX];
            for (int i = tid; i < 196; i += TPB) d[i] = xg[i];
        }
        __syncthreads();

        // ---- conv7 (28->22) + pool (->11) + relu ----
        // oc = tid&7 -> 8-lane broadcast; x rows as float2 (start 10h even).
        if (tid < 176) {
            int oc = tid & 7;
            int r  = tid >> 3;
            int py = r >> 1;
            int h  = r & 1;
            const int cc0 = 10 * h;
            float c[2][12];
            #pragma unroll
            for (int r2 = 0; r2 < 2; ++r2)
                #pragma unroll
                for (int i = 0; i < 12; ++i) c[r2][i] = 0.f;
            float wc[7], wp[7];
            const float* wg = kf_w1 + oc * 49;
            #pragma unroll
            for (int i = 0; i < 7; ++i) wc[i] = wg[i];
            #pragma unroll
            for (int t = 0; t < 8; ++t) {
                const float2* xs = (const float2*)&sm[OX + (2 * py + t) * 28 + cc0];
                float row[18];
                #pragma unroll
                for (int i = 0; i < 9; ++i) { float2 q = xs[i]; row[2*i] = q.x; row[2*i+1] = q.y; }
                if (t <= 6) {
                    #pragma unroll
                    for (int kx = 0; kx < 7; ++kx)
                        #pragma unroll
                        for (int cc = 0; cc < 12; ++cc)
                            c[0][cc] = fmaf(wc[kx], row[cc + kx], c[0][cc]);
                }
                if (t >= 1) {
                    #pragma unroll
                    for (int kx = 0; kx < 7; ++kx)
                        #pragma unroll
                        for (int cc = 0; cc < 12; ++cc)
                            c[1][cc] = fmaf(wp[kx], row[cc + kx], c[1][cc]);
                }
                #pragma unroll
                for (int i = 0; i < 7; ++i) wp[i] = wc[i];
                if (t < 7) {
                    const float* wn = wg + (t + 1) * 7;
                    #pragma unroll
                    for (int i = 0; i < 7; ++i) wc[i] = wn[i];
                }
            }
            float b = kf_b1[oc];
            #pragma unroll
            for (int j = 0; j < 6; ++j) {
                float m = fmaxf(fmaxf(c[0][2 * j], c[0][2 * j + 1]),
                                fmaxf(c[1][2 * j], c[1][2 * j + 1]));
                sm[OC1 + oc * 132 + py * 12 + 5 * h + j] = fmaxf(m + b, 0.f);
            }
        }
        __syncthreads();

        // ---- conv5 (11->7) + pool (->3) + relu; c1 rows as float2 ----
        if (tid < 90) {
            int oc = tid % 10, r = tid / 10;
            int py = r / 3, px = r % 3;
            float a00 = 0.f, a01 = 0.f, a10 = 0.f, a11 = 0.f;
            for (int ic = 0; ic < 8; ++ic) {
                float w[25];
                const float* wg = kf_w2 + (oc * 8 + ic) * 25;
                #pragma unroll
                for (int i = 0; i < 25; ++i) w[i] = wg[i];
                const float* xb = &sm[OC1 + ic * 132 + 2 * py * 12 + 2 * px];
                float cur[6], nxt[6];
                {
                    const float2* xr = (const float2*)xb;
                    #pragma unroll
                    for (int i = 0; i < 3; ++i) { float2 q = xr[i]; cur[2*i] = q.x; cur[2*i+1] = q.y; }
                }
                #pragma unroll
                for (int ky = 0; ky < 5; ++ky) {
                    const float2* xr = (const float2*)(xb + (ky + 1) * 12);
                    #pragma unroll
                    for (int i = 0; i < 3; ++i) { float2 q = xr[i]; nxt[2*i] = q.x; nxt[2*i+1] = q.y; }
                    #pragma unroll
                    for (int kx = 0; kx < 5; ++kx) {
                        float wv = w[ky * 5 + kx];
                        a00 = fmaf(wv, cur[kx],     a00);
                        a01 = fmaf(wv, cur[kx + 1], a01);
                        a10 = fmaf(wv, nxt[kx],     a10);
                        a11 = fmaf(wv, nxt[kx + 1], a11);
                    }
                    #pragma unroll
                    for (int i = 0; i < 6; ++i) cur[i] = nxt[i];
                }
            }
            float m = fmaxf(fmaxf(a00, a01), fmaxf(a10, a11)) + kf_b2[oc];
            sm[OF + oc * 9 + py * 3 + px] = fmaxf(m, 0.f);
        }
        __syncthreads();

        // ---- fc 90->32 + relu, then fc 32->40: same wave, no barrier ----
        if (tid < 32) {
            float acc = kf_fc1_b[tid];
            const float2* wr = (const float2*)&kf_fc1_w[tid * 90];
            const float2* ff = (const float2*)&sm[OF];
            for (int i = 0; i < 45; ++i) {
                float2 wv = wr[i], fv = ff[i];
                acc = fmaf(wv.x, fv.x, acc);
                acc = fmaf(wv.y, fv.y, acc);
            }
            sm[OH + tid] = fmaxf(acc, 0.f);
        }
        if (tid < 40) {
            float acc = kf_fc2_b[tid];
            const float4* wr = (const float4*)&kf_fc2_w[tid * 32];
            const float4* hh = (const float4*)&sm[OH];
            #pragma unroll
            for (int i = 0; i < 8; ++i) {
                float4 wv = wr[i], hv = hh[i];
                acc = fmaf(wv.x, hv.x, acc);
                acc = fmaf(wv.y, hv.y, acc);
                acc = fmaf(wv.z, hv.z, acc);
                acc = fmaf(wv.w, hv.w, acc);
            }
            sm[OK2 + tid] = acc;
        }
        __syncthreads();

        // ---- dynamic 2x2 conv + pool + relu; 12x12 live region only ----
        if (tid < 120) {
            int oc = tid % 10, py = tid / 10;
            float4 kv = *(const float4*)&sm[OK2 + oc * 4];
            float k0 = kv.x, k1 = kv.y, k2 = kv.z, k3 = kv.w;
            const float* x0 = &sm[OX + 2 * py * 28];
            const float* x1 = x0 + 28;
            const float* x2 = x0 + 56;
            float2 q0 = *(const float2*)&x0[0];
            float2 q1 = *(const float2*)&x1[0];
            float2 q2 = *(const float2*)&x2[0];
            float A0 = q0.x, B0 = q0.y;
            float A1 = q1.x, B1 = q1.y;
            float A2 = q2.x, B2 = q2.y;
            float* yo = &sm[OY + oc * YIC + py * 12];
            #pragma unroll
            for (int j = 0; j < 12; ++j) {
                float2 r0 = *(const float2*)&x0[2 * j + 2];
                float2 r1 = *(const float2*)&x1[2 * j + 2];
                float2 r2 = *(const float2*)&x2[2 * j + 2];
                float C0 = r0.x, C1 = r1.x, C2 = r2.x;
                float c00 = A0 * k0 + B0 * k1 + A1 * k2 + B1 * k3;
                float c01 = B0 * k0 + C0 * k1 + B1 * k2 + C1 * k3;
                float c10 = A1 * k0 + B1 * k1 + A2 * k2 + B2 * k3;
                float c11 = B1 * k0 + C1 * k1 + B2 * k2 + C2 * k3;
                float m = fmaxf(fmaxf(c00, c01), fmaxf(c10, c11));
                yo[j] = fmaxf(m, 0.f);
                A0 = C0; A1 = C1; A2 = C2;
                B0 = r0.y; B1 = r1.y; B2 = r2.y;
            }
        }
        __syncthreads();

        // ---- conv2 5x5: 8x8 pooled-live outputs; y rows as 3x float4.
        // h2=0 writes partials to P2; h2=1 keeps acc in regs across barrier.
        const int oc2 = tid % 20;
        const int q2i = tid / 20;
        const int h2  = q2i & 1;
        const int rg2 = q2i >> 1;
        float a2[2][8];
        if (tid < 160) {
            int r0 = 2 * rg2;
            #pragma unroll
            for (int r = 0; r < 2; ++r)
                #pragma unroll
                for (int i = 0; i < 8; ++i) a2[r][i] = 0.f;
            for (int icg = 0; icg < 5; ++icg) {
                int ic = 5 * h2 + icg;
                float w[25];
                const float* wg = conv2_w + (oc2 * 10 + ic) * 25;
                #pragma unroll
                for (int i = 0; i < 25; ++i) w[i] = wg[i];
                const float* yb = &sm[OY + ic * YIC + r0 * 12];
                float row[12];
                #pragma unroll
                for (int u = 0; u < 6; ++u) {
                    const float4* ys = (const float4*)(yb + u * 12);
                    #pragma unroll
                    for (int i = 0; i < 3; ++i) {
                        float4 q = ys[i];
                        row[4*i] = q.x; row[4*i+1] = q.y; row[4*i+2] = q.z; row[4*i+3] = q.w;
                    }
                    #pragma unroll
                    for (int rr = 0; rr < 2; ++rr) {
                        int ky = u - rr;
                        if (ky >= 0 && ky <= 4) {
                            #pragma unroll
                            for (int kx = 0; kx < 5; ++kx)
                                #pragma unroll
                                for (int cx = 0; cx < 8; ++cx)
                                    a2[rr][cx] = fmaf(w[ky * 5 + kx], row[cx + kx], a2[rr][cx]);
                        }
                    }
                }
            }
            if (h2 == 0) {
                int r0w = 2 * rg2;
                #pragma unroll
                for (int rr = 0; rr < 2; ++rr)
                    #pragma unroll
                    for (int cx = 0; cx < 8; ++cx)
                        sm[OP2 + oc2 * 65 + (r0w + rr) * 8 + cx] = a2[rr][cx];
            }
        }
        __syncthreads();

        // ---- combine halves + bias + pool + relu -> p3[20,4,4] ----
        if (tid < 160 && h2 == 1) {
            float b = conv2_b[oc2];
            const float* p0 = &sm[OP2 + oc2 * 65 + (2 * rg2) * 8];
            #pragma unroll
            for (int px = 0; px < 4; ++px) {
                float c00 = b + a2[0][2 * px]     + p0[2 * px];
                float c01 = b + a2[0][2 * px + 1] + p0[2 * px + 1];
                float c10 = b + a2[1][2 * px]     + p0[8 + 2 * px];
                float c11 = b + a2[1][2 * px + 1] + p0[8 + 2 * px + 1];
                float m = fmaxf(fmaxf(c00, c01), fmaxf(c10, c11));
                sm[OP3 + oc2 * 16 + rg2 * 4 + px] = fmaxf(m, 0.f);
            }
        }
        __syncthreads();

        // ---- fc 320->50, 2-way k-split (100 threads, 40 float4 each) ----
        if (tid < 100) {
            int g = tid / 50, o = tid % 50;
            const float4* wr4 = (const float4*)&fc1_w[o * 320 + g * 160];
            const float4* pp4 = (const float4*)&sm[OP3 + g * 160];
            float acc = 0.f;
            for (int i = 0; i < 40; ++i) {
                float4 wv = wr4[i], pv = pp4[i];
                acc = fmaf(wv.x, pv.x, acc);
                acc = fmaf(wv.y, pv.y, acc);
                acc = fmaf(wv.z, pv.z, acc);
                acc = fmaf(wv.w, pv.w, acc);
            }
            sm[OPF + tid] = acc;
        }
        __syncthreads();

        // ---- tail: wave 0, barrier-free (intra-wave LDS ordering) ----
        if (tid < 50) {
            float acc = fc1_b[tid] + sm[OPF + tid] + sm[OPF + 50 + tid];
            sm[OA1 + tid] = fmaxf(acc, 0.f);
        }
        if (tid < 10) {
            float acc = fc2_b[tid];
            const float2* wr = (const float2*)&fc2_w[tid * 50];
            #pragma unroll
            for (int i = 0; i < 25; ++i) {
                float2 wv = wr[i];
                acc = fmaf(wv.x, sm[OA1 + 2 * i], acc);
                acc = fmaf(wv.y, sm[OA1 + 2 * i + 1], acc);
            }
            sm[OZ + tid] = acc;
        }
        if (tid < 10) {
            float m = sm[OZ + 0];
            #pragma unroll
            for (int i = 1; i < 10; ++i) m = fmaxf(m, sm[OZ + i]);
            float s = 0.f;
            #pragma unroll
            for (int i = 0; i < 10; ++i) s += expf(sm[OZ + i] - m);
            out[n * 10 + tid] = sm[OZ + tid] - m - logf(s);
        }
    }
}

extern "C" void kernel_launch(void* const* d_in, const int* in_sizes, int n_in,
                              void* d_out, int out_size, void* d_ws, size_t ws_size,
                              hipStream_t stream) {
    const float* x        = (const float*)d_in[0];
    const float* kf_w1    = (const float*)d_in[1];
    const float* kf_b1    = (const float*)d_in[2];
    const float* kf_w2    = (const float*)d_in[3];
    const float* kf_b2    = (const float*)d_in[4];
    const float* kf_fc1_w = (const float*)d_in[5];
    const float* kf_fc1_b = (const float*)d_in[6];
    const float* kf_fc2_w = (const float*)d_in[7];
    const float* kf_fc2_b = (const float*)d_in[8];
    const float* conv2_w  = (const float*)d_in[9];
    const float* conv2_b  = (const float*)d_in[10];
    const float* fc1_w    = (const float*)d_in[11];
    const float* fc1_b    = (const float*)d_in[12];
    const float* fc2_w    = (const float*)d_in[13];
    const float* fc2_b    = (const float*)d_in[14];

    const int N = in_sizes[0] / 784;   // 8192

    fused_forward<<<N / SPB, TPB, 0, stream>>>(
        x, kf_w1, kf_b1, kf_w2, kf_b2, kf_fc1_w, kf_fc1_b, kf_fc2_w, kf_fc2_b,
        conv2_w, conv2_b, fc1_w, fc1_b, fc2_w, fc2_b, (float*)d_out);
}

// Round 9
// 304.074 us; speedup vs baseline: 1.2649x; 1.2649x over previous
//
#include <hip/hip_runtime.h>
#include <math.h>

#define TPB 192

// ---- LDS layout (float offsets), lifetime-overlaid; identical to R6. ----
// x   [0,784)   c1 [784,1840) [8][11][12]   f [1840,1930)   h [1932,1964)
// y   [784,2264) [10][12][12] ic-stride 148   k [2264,2304)
// P2  [2304,3604) [20][65]
// p3 [0,320) pf [320,420) a1 [420,470) z [472,482)  (over dead x)
#define OX    0
#define OC1   784
#define OF    1840
#define OH    1932
#define OY    784
#define YIC   148
#define OK2   2264
#define OP2   2304
#define OP3   0
#define OPF   320
#define OA1   420
#define OZ    472
#define SM_TOT 3604   // 14416 B

// R9: packed-FP32 FMA. The kernel is ~95% VALU-issue-bound (R8 post-mortem:
// 384K cyc/SIMD modeled vs 152us busy measured). v_pk_fma_f32 (CDNA dual-
// pump fp32 — the reason MI355X's fp32 spec is 157 TF, 2x the plain rate)
// halves the FMA instruction count. Pairing: acc = {pool-row0, pool-row1}
// (same input row, weights one ky apart -> weight pairs from rolling loads);
// input row operand = existing float2 regs with op_sel dword-broadcast (no
// movs). fc layers pack over k-pairs. Everything else byte-identical to R6.
__device__ __forceinline__ void pk_fma(float2& d, float2 a, float2 b) {
    asm("v_pk_fma_f32 %0, %1, %2, %0" : "+v"(d) : "v"(a), "v"(b));
}
// b's LOW dword broadcast to both halves
__device__ __forceinline__ void pk_fma_lo(float2& d, float2 a, float2 b) {
    asm("v_pk_fma_f32 %0, %1, %2, %0 op_sel:[0,0,0] op_sel_hi:[1,0,1]"
        : "+v"(d) : "v"(a), "v"(b));
}
// b's HIGH dword broadcast to both halves
__device__ __forceinline__ void pk_fma_hi(float2& d, float2 a, float2 b) {
    asm("v_pk_fma_f32 %0, %1, %2, %0 op_sel:[0,1,0] op_sel_hi:[1,1,1]"
        : "+v"(d) : "v"(a), "v"(b));
}

__global__ __launch_bounds__(TPB) void fused_forward(
    const float* __restrict__ x,
    const float* __restrict__ kf_w1, const float* __restrict__ kf_b1,
    const float* __restrict__ kf_w2, const float* __restrict__ kf_b2,
    const float* __restrict__ kf_fc1_w, const float* __restrict__ kf_fc1_b,
    const float* __restrict__ kf_fc2_w, const float* __restrict__ kf_fc2_b,
    const float* __restrict__ conv2_w, const float* __restrict__ conv2_b,
    const float* __restrict__ fc1_w, const float* __restrict__ fc1_b,
    const float* __restrict__ fc2_w, const float* __restrict__ fc2_b,
    float* __restrict__ out)
{
    __shared__ __align__(16) float sm[SM_TOT];
    const int tid = threadIdx.x;
    const int n = blockIdx.x;

    // ---- stage 0: stage x into LDS (float4) ----
    {
        const float4* xg = (const float4*)(x + (long long)n * 784);
        float4* d = (float4*)&sm[OX];
        for (int i = tid; i < 196; i += TPB) d[i] = xg[i];
    }
    __syncthreads();

    // ---- conv7 (28->22) + pool (->11) + relu ----
    // acc pair c2[cc] = {pool-row0, pool-row1}. Input row t feeds row0 via
    // w-row t (t<=6) and row1 via w-row t-1 (t>=1) -> wpair {wcur,wprev}.
    if (tid < 176) {
        int oc = tid & 7;
        int r  = tid >> 3;
        int py = r >> 1;
        int h  = r & 1;
        const int cc0 = 10 * h;
        float2 c2[12];
        #pragma unroll
        for (int i = 0; i < 12; ++i) c2[i] = float2{0.f, 0.f};
        const float* wg = kf_w1 + oc * 49;
        float wcur[7], wprev[7];
        #pragma unroll
        for (int i = 0; i < 7; ++i) wcur[i] = wg[i];
        float2 r2[9];
        // t = 0: row0 only (scalar into .x)
        {
            const float2* xs = (const float2*)&sm[OX + (2 * py) * 28 + cc0];
            #pragma unroll
            for (int i = 0; i < 9; ++i) r2[i] = xs[i];
            #pragma unroll
            for (int kx = 0; kx < 7; ++kx)
                #pragma unroll
                for (int cc = 0; cc < 12; ++cc) {
                    int j = cc + kx;
                    float rv = (j & 1) ? r2[j >> 1].y : r2[j >> 1].x;
                    c2[cc].x = fmaf(wcur[kx], rv, c2[cc].x);
                }
        }
        // t = 1..6: both rows -> packed
        #pragma unroll
        for (int t = 1; t <= 6; ++t) {
            #pragma unroll
            for (int i = 0; i < 7; ++i) wprev[i] = wcur[i];
            const float* wn = wg + t * 7;
            #pragma unroll
            for (int i = 0; i < 7; ++i) wcur[i] = wn[i];
            const float2* xs = (const float2*)&sm[OX + (2 * py + t) * 28 + cc0];
            #pragma unroll
            for (int i = 0; i < 9; ++i) r2[i] = xs[i];
            #pragma unroll
            for (int kx = 0; kx < 7; ++kx) {
                float2 wp2{wcur[kx], wprev[kx]};
                #pragma unroll
                for (int cc = 0; cc < 12; ++cc) {
                    int j = cc + kx;
                    if (j & 1) pk_fma_hi(c2[cc], wp2, r2[j >> 1]);
                    else       pk_fma_lo(c2[cc], wp2, r2[j >> 1]);
                }
            }
        }
        // t = 7: row1 only with w-row 6 (= wcur), scalar into .y
        {
            const float2* xs = (const float2*)&sm[OX + (2 * py + 7) * 28 + cc0];
            #pragma unroll
            for (int i = 0; i < 9; ++i) r2[i] = xs[i];
            #pragma unroll
            for (int kx = 0; kx < 7; ++kx)
                #pragma unroll
                for (int cc = 0; cc < 12; ++cc) {
                    int j = cc + kx;
                    float rv = (j & 1) ? r2[j >> 1].y : r2[j >> 1].x;
                    c2[cc].y = fmaf(wcur[kx], rv, c2[cc].y);
                }
        }
        float b = kf_b1[oc];
        #pragma unroll
        for (int j = 0; j < 6; ++j) {
            float m = fmaxf(fmaxf(c2[2 * j].x, c2[2 * j + 1].x),
                            fmaxf(c2[2 * j].y, c2[2 * j + 1].y));
            sm[OC1 + oc * 132 + py * 12 + 5 * h + j] = fmaxf(m + b, 0.f);
        }
    }
    __syncthreads();

    // ---- conv5 (11->7) + pool (->3) + relu; packed over pool rows ----
    // pa = {a00, a10}, pb = {a01, a11}; staged row u (0..5) feeds a0x via
    // w-row u, a1x via w-row u-1.
    if (tid < 90) {
        int oc = tid % 10, r = tid / 10;
        int py = r / 3, px = r % 3;
        float2 pa{0.f, 0.f}, pb{0.f, 0.f};
        for (int ic = 0; ic < 8; ++ic) {
            const float* wg = kf_w2 + (oc * 8 + ic) * 25;
            const float* xb = &sm[OC1 + ic * 132 + 2 * py * 12 + 2 * px];
            float wcur[5], wprev[5];
            #pragma unroll
            for (int i = 0; i < 5; ++i) wcur[i] = wg[i];
            float2 r2[3];
            {
                const float2* xr = (const float2*)xb;
                r2[0] = xr[0]; r2[1] = xr[1]; r2[2] = xr[2];
            }
            #pragma unroll
            for (int kx = 0; kx < 5; ++kx) {
                float rv0 = (kx & 1) ? r2[kx >> 1].y : r2[kx >> 1].x;
                int k1 = kx + 1;
                float rv1 = (k1 & 1) ? r2[k1 >> 1].y : r2[k1 >> 1].x;
                pa.x = fmaf(wcur[kx], rv0, pa.x);
                pb.x = fmaf(wcur[kx], rv1, pb.x);
            }
            #pragma unroll
            for (int u = 1; u <= 4; ++u) {
                #pragma unroll
                for (int i = 0; i < 5; ++i) wprev[i] = wcur[i];
                const float* wn = wg + u * 5;
                #pragma unroll
                for (int i = 0; i < 5; ++i) wcur[i] = wn[i];
                const float2* xr = (const float2*)(xb + u * 12);
                r2[0] = xr[0]; r2[1] = xr[1]; r2[2] = xr[2];
                #pragma unroll
                for (int kx = 0; kx < 5; ++kx) {
                    float2 wp2{wcur[kx], wprev[kx]};
                    if (kx & 1) pk_fma_hi(pa, wp2, r2[kx >> 1]);
                    else        pk_fma_lo(pa, wp2, r2[kx >> 1]);
                    int k1 = kx + 1;
                    if (k1 & 1) pk_fma_hi(pb, wp2, r2[k1 >> 1]);
                    else        pk_fma_lo(pb, wp2, r2[k1 >> 1]);
                }
            }
            {
                const float2* xr = (const float2*)(xb + 5 * 12);
                r2[0] = xr[0]; r2[1] = xr[1]; r2[2] = xr[2];
                #pragma unroll
                for (int kx = 0; kx < 5; ++kx) {
                    float rv0 = (kx & 1) ? r2[kx >> 1].y : r2[kx >> 1].x;
                    int k1 = kx + 1;
                    float rv1 = (k1 & 1) ? r2[k1 >> 1].y : r2[k1 >> 1].x;
                    pa.y = fmaf(wcur[kx], rv0, pa.y);
                    pb.y = fmaf(wcur[kx], rv1, pb.y);
                }
            }
        }
        float m = fmaxf(fmaxf(pa.x, pb.x), fmaxf(pa.y, pb.y)) + kf_b2[oc];
        sm[OF + oc * 9 + py * 3 + px] = fmaxf(m, 0.f);
    }
    __syncthreads();

    // ---- fc 90->32 + relu, then fc 32->40: same wave, no barrier; packed ----
    if (tid < 32) {
        const float2* wr = (const float2*)&kf_fc1_w[tid * 90];
        const float2* ff = (const float2*)&sm[OF];
        float2 acc2{0.f, 0.f};
        for (int i = 0; i < 45; ++i) pk_fma(acc2, wr[i], ff[i]);
        sm[OH + tid] = fmaxf(kf_fc1_b[tid] + acc2.x + acc2.y, 0.f);
    }
    if (tid < 40) {
        const float4* wr = (const float4*)&kf_fc2_w[tid * 32];
        const float4* hh = (const float4*)&sm[OH];
        float2 acc2{0.f, 0.f};
        #pragma unroll
        for (int i = 0; i < 8; ++i) {
            float4 wv = wr[i], hv = hh[i];
            pk_fma(acc2, float2{wv.x, wv.y}, float2{hv.x, hv.y});
            pk_fma(acc2, float2{wv.z, wv.w}, float2{hv.z, hv.w});
        }
        sm[OK2 + tid] = kf_fc2_b[tid] + acc2.x + acc2.y;
    }
    __syncthreads();

    // ---- dynamic 2x2 conv + pool + relu; 12x12 live region (scalar) ----
    if (tid < 120) {
        int oc = tid % 10, py = tid / 10;
        float4 kv = *(const float4*)&sm[OK2 + oc * 4];
        float k0 = kv.x, k1 = kv.y, k2 = kv.z, k3 = kv.w;
        const float* x0 = &sm[OX + 2 * py * 28];
        const float* x1 = x0 + 28;
        const float* x2 = x0 + 56;
        float2 q0 = *(const float2*)&x0[0];
        float2 q1 = *(const float2*)&x1[0];
        float2 q2 = *(const float2*)&x2[0];
        float A0 = q0.x, B0 = q0.y;
        float A1 = q1.x, B1 = q1.y;
        float A2 = q2.x, B2 = q2.y;
        float* yo = &sm[OY + oc * YIC + py * 12];
        #pragma unroll
        for (int j = 0; j < 12; ++j) {
            float2 r0 = *(const float2*)&x0[2 * j + 2];
            float2 r1 = *(const float2*)&x1[2 * j + 2];
            float2 r2v = *(const float2*)&x2[2 * j + 2];
            float C0 = r0.x, C1 = r1.x, C2 = r2v.x;
            float c00 = A0 * k0 + B0 * k1 + A1 * k2 + B1 * k3;
            float c01 = B0 * k0 + C0 * k1 + B1 * k2 + C1 * k3;
            float c10 = A1 * k0 + B1 * k1 + A2 * k2 + B2 * k3;
            float c11 = B1 * k0 + C1 * k1 + B2 * k2 + C2 * k3;
            float m = fmaxf(fmaxf(c00, c01), fmaxf(c10, c11));
            yo[j] = fmaxf(m, 0.f);
            A0 = C0; A1 = C1; A2 = C2;
            B0 = r0.y; B1 = r1.y; B2 = r2v.y;
        }
    }
    __syncthreads();

    // ---- conv2 5x5 packed: acc2[cx] = {out-row r0, out-row r0+1}.
    // Staged row u (0..5) feeds row0 via w-row u, row1 via w-row u-1.
    // h2=0 writes partials to P2; h2=1 keeps acc2 in regs across barrier.
    const int oc2 = tid % 20;
    const int q2i = tid / 20;
    const int h2  = q2i & 1;
    const int rg2 = q2i >> 1;
    float2 acc2c[8];
    if (tid < 160) {
        int r0 = 2 * rg2;
        #pragma unroll
        for (int i = 0; i < 8; ++i) acc2c[i] = float2{0.f, 0.f};
        for (int icg = 0; icg < 5; ++icg) {
            int ic = 5 * h2 + icg;
            const float* wg = conv2_w + (oc2 * 10 + ic) * 25;
            const float* yb = &sm[OY + ic * YIC + r0 * 12];
            float wcur[5], wprev[5];
            #pragma unroll
            for (int i = 0; i < 5; ++i) wcur[i] = wg[i];
            float2 r2[6];
            // u = 0: row0 only (scalar into .x)
            {
                const float4* ys = (const float4*)yb;
                float4 q0 = ys[0], q1 = ys[1], q2 = ys[2];
                r2[0] = float2{q0.x, q0.y}; r2[1] = float2{q0.z, q0.w};
                r2[2] = float2{q1.x, q1.y}; r2[3] = float2{q1.z, q1.w};
                r2[4] = float2{q2.x, q2.y}; r2[5] = float2{q2.z, q2.w};
                #pragma unroll
                for (int kx = 0; kx < 5; ++kx)
                    #pragma unroll
                    for (int cx = 0; cx < 8; ++cx) {
                        int j = cx + kx;
                        float rv = (j & 1) ? r2[j >> 1].y : r2[j >> 1].x;
                        acc2c[cx].x = fmaf(wcur[kx], rv, acc2c[cx].x);
                    }
            }
            // u = 1..4: both rows -> packed
            #pragma unroll
            for (int u = 1; u <= 4; ++u) {
                #pragma unroll
                for (int i = 0; i < 5; ++i) wprev[i] = wcur[i];
                const float* wn = wg + u * 5;
                #pragma unroll
                for (int i = 0; i < 5; ++i) wcur[i] = wn[i];
                const float4* ys = (const float4*)(yb + u * 12);
                float4 q0 = ys[0], q1 = ys[1], q2 = ys[2];
                r2[0] = float2{q0.x, q0.y}; r2[1] = float2{q0.z, q0.w};
                r2[2] = float2{q1.x, q1.y}; r2[3] = float2{q1.z, q1.w};
                r2[4] = float2{q2.x, q2.y}; r2[5] = float2{q2.z, q2.w};
                #pragma unroll
                for (int kx = 0; kx < 5; ++kx) {
                    float2 wp2{wcur[kx], wprev[kx]};
                    #pragma unroll
                    for (int cx = 0; cx < 8; ++cx) {
                        int j = cx + kx;
                        if (j & 1) pk_fma_hi(acc2c[cx], wp2, r2[j >> 1]);
                        else       pk_fma_lo(acc2c[cx], wp2, r2[j >> 1]);
                    }
                }
            }
            // u = 5: row1 only with w-row 4 (= wcur), scalar into .y
            {
                const float4* ys = (const float4*)(yb + 5 * 12);
                float4 q0 = ys[0], q1 = ys[1], q2 = ys[2];
                r2[0] = float2{q0.x, q0.y}; r2[1] = float2{q0.z, q0.w};
                r2[2] = float2{q1.x, q1.y}; r2[3] = float2{q1.z, q1.w};
                r2[4] = float2{q2.x, q2.y}; r2[5] = float2{q2.z, q2.w};
                #pragma unroll
                for (int kx = 0; kx < 5; ++kx)
                    #pragma unroll
                    for (int cx = 0; cx < 8; ++cx) {
                        int j = cx + kx;
                        float rv = (j & 1) ? r2[j >> 1].y : r2[j >> 1].x;
                        acc2c[cx].y = fmaf(wcur[kx], rv, acc2c[cx].y);
                    }
            }
        }
        if (h2 == 0) {
            int r0w = 2 * rg2;
            #pragma unroll
            for (int cx = 0; cx < 8; ++cx) {
                sm[OP2 + oc2 * 65 + r0w * 8 + cx]       = acc2c[cx].x;
                sm[OP2 + oc2 * 65 + (r0w + 1) * 8 + cx] = acc2c[cx].y;
            }
        }
    }
    __syncthreads();

    // ---- combine halves + bias + pool + relu -> p3[20,4,4] ----
    if (tid < 160 && h2 == 1) {
        float b = conv2_b[oc2];
        const float* p0 = &sm[OP2 + oc2 * 65 + (2 * rg2) * 8];
        #pragma unroll
        for (int px = 0; px < 4; ++px) {
            float c00 = b + acc2c[2 * px].x     + p0[2 * px];
            float c01 = b + acc2c[2 * px + 1].x + p0[2 * px + 1];
            float c10 = b + acc2c[2 * px].y     + p0[8 + 2 * px];
            float c11 = b + acc2c[2 * px + 1].y + p0[8 + 2 * px + 1];
            float m = fmaxf(fmaxf(c00, c01), fmaxf(c10, c11));
            sm[OP3 + oc2 * 16 + rg2 * 4 + px] = fmaxf(m, 0.f);
        }
    }
    __syncthreads();

    // ---- fc 320->50, 2-way k-split, packed (100 threads, 40 float4 each) ----
    if (tid < 100) {
        int g = tid / 50, o = tid % 50;
        const float4* wr4 = (const float4*)&fc1_w[o * 320 + g * 160];
        const float4* pp4 = (const float4*)&sm[OP3 + g * 160];
        float2 acc2{0.f, 0.f};
        for (int i = 0; i < 40; ++i) {
            float4 wv = wr4[i], pv = pp4[i];
            pk_fma(acc2, float2{wv.x, wv.y}, float2{pv.x, pv.y});
            pk_fma(acc2, float2{wv.z, wv.w}, float2{pv.z, pv.w});
        }
        sm[OPF + tid] = acc2.x + acc2.y;
    }
    __syncthreads();

    // ---- tail: wave 0, barrier-free (intra-wave LDS ordering) ----
    if (tid < 50) {
        float acc = fc1_b[tid] + sm[OPF + tid] + sm[OPF + 50 + tid];
        sm[OA1 + tid] = fmaxf(acc, 0.f);
    }
    if (tid < 10) {
        const float2* wr = (const float2*)&fc2_w[tid * 50];
        const float2* aa = (const float2*)&sm[OA1];          // OA1 even
        float2 acc2{0.f, 0.f};
        #pragma unroll
        for (int i = 0; i < 25; ++i) pk_fma(acc2, wr[i], aa[i]);
        sm[OZ + tid] = fc2_b[tid] + acc2.x + acc2.y;
    }
    if (tid < 10) {
        float m = sm[OZ + 0];
        #pragma unroll
        for (int i = 1; i < 10; ++i) m = fmaxf(m, sm[OZ + i]);
        float s = 0.f;
        #pragma unroll
        for (int i = 0; i < 10; ++i) s += expf(sm[OZ + i] - m);
        out[n * 10 + tid] = sm[OZ + tid] - m - logf(s);
    }
}

extern "C" void kernel_launch(void* const* d_in, const int* in_sizes, int n_in,
                              void* d_out, int out_size, void* d_ws, size_t ws_size,
                              hipStream_t stream) {
    const float* x        = (const float*)d_in[0];
    const float* kf_w1    = (const float*)d_in[1];
    const float* kf_b1    = (const float*)d_in[2];
    const float* kf_w2    = (const float*)d_in[3];
    const float* kf_b2    = (const float*)d_in[4];
    const float* kf_fc1_w = (const float*)d_in[5];
    const float* kf_fc1_b = (const float*)d_in[6];
    const float* kf_fc2_w = (const float*)d_in[7];
    const float* kf_fc2_b = (const float*)d_in[8];
    const float* conv2_w  = (const float*)d_in[9];
    const float* conv2_b  = (const float*)d_in[10];
    const float* fc1_w    = (const float*)d_in[11];
    const float* fc1_b    = (const float*)d_in[12];
    const float* fc2_w    = (const float*)d_in[13];
    const float* fc2_b    = (const float*)d_in[14];

    const int N = in_sizes[0] / 784;   // 8192

    fused_forward<<<N, TPB, 0, stream>>>(
        x, kf_w1, kf_b1, kf_w2, kf_b2, kf_fc1_w, kf_fc1_b, kf_fc2_w, kf_fc2_b,
        conv2_w, conv2_b, fc1_w, fc1_b, fc2_w, fc2_b, (float*)d_out);
}

// Round 10
// 281.841 us; speedup vs baseline: 1.3647x; 1.0789x over previous
//
#include <hip/hip_runtime.h>
#include <math.h>

#define TPB 192

// ---- LDS layout (float offsets), lifetime-overlaid; identical to R6. ----
// x   [0,784)   c1 [784,1840) [8][11][12]   f [1840,1930)   h [1932,1964)
// y   [784,2264) [10][12][12] ic-stride 148   k [2264,2304)
// P2  [2304,3604) [20][65]  (conv2 partials; ALSO reused during conv5 as
//                  p5[360]: conv5 h0-half's 4 pre-pool partials x 90 threads)
// p3 [0,320) pf [320,420) a1 [420,470) z [472,482)  (over dead x)
#define OX    0
#define OC1   784
#define OF    1840
#define OH    1932
#define OY    784
#define YIC   148
#define OK2   2264
#define OP2   2304
#define OP3   0
#define OPF   320
#define OA1   420
#define OZ    472
#define SM_TOT 3604   // 14416 B

// R10: R6 revert (R9's v_pk_fma_f32 is a dead end: CDNA4's 157.3 TF fp32
// spec = plain-FMA rate on 4x SIMD-32; pk takes 2x cycles, zero FLOP gain,
// and the inline asm added stalls 69->112us) + conv5 lane-split: 90 thr x
// 800 FMA (wave1 41% full, wave2 idle) -> 180 thr x 400 FMA over ic-halves.
// Pre-pool partials can't be maxed separately: h0 writes its 4 partials to
// LDS (float4, dead-P2 region), h1 keeps 4 in regs across the barrier and
// combines (conv2's proven reg-carry pattern). +1 barrier, -400 wave-inst.
__global__ __launch_bounds__(TPB) void fused_forward(
    const float* __restrict__ x,
    const float* __restrict__ kf_w1, const float* __restrict__ kf_b1,
    const float* __restrict__ kf_w2, const float* __restrict__ kf_b2,
    const float* __restrict__ kf_fc1_w, const float* __restrict__ kf_fc1_b,
    const float* __restrict__ kf_fc2_w, const float* __restrict__ kf_fc2_b,
    const float* __restrict__ conv2_w, const float* __restrict__ conv2_b,
    const float* __restrict__ fc1_w, const float* __restrict__ fc1_b,
    const float* __restrict__ fc2_w, const float* __restrict__ fc2_b,
    float* __restrict__ out)
{
    __shared__ __align__(16) float sm[SM_TOT];
    const int tid = threadIdx.x;
    const int n = blockIdx.x;

    // ---- stage 0: stage x into LDS (float4) ----
    {
        const float4* xg = (const float4*)(x + (long long)n * 784);
        float4* d = (float4*)&sm[OX];
        for (int i = tid; i < 196; i += TPB) d[i] = xg[i];
    }
    __syncthreads();

    // ---- conv7 (28->22) + pool (->11) + relu ----
    // oc = tid&7 -> 8-lane broadcast; x rows as float2 (start 10h even).
    if (tid < 176) {
        int oc = tid & 7;
        int r  = tid >> 3;
        int py = r >> 1;
        int h  = r & 1;
        const int cc0 = 10 * h;
        float c[2][12];
        #pragma unroll
        for (int r2 = 0; r2 < 2; ++r2)
            #pragma unroll
            for (int i = 0; i < 12; ++i) c[r2][i] = 0.f;
        float wc[7], wp[7];
        const float* wg = kf_w1 + oc * 49;
        #pragma unroll
        for (int i = 0; i < 7; ++i) wc[i] = wg[i];
        #pragma unroll
        for (int t = 0; t < 8; ++t) {
            const float2* xs = (const float2*)&sm[OX + (2 * py + t) * 28 + cc0];
            float row[18];
            #pragma unroll
            for (int i = 0; i < 9; ++i) { float2 q = xs[i]; row[2*i] = q.x; row[2*i+1] = q.y; }
            if (t <= 6) {
                #pragma unroll
                for (int kx = 0; kx < 7; ++kx)
                    #pragma unroll
                    for (int cc = 0; cc < 12; ++cc)
                        c[0][cc] = fmaf(wc[kx], row[cc + kx], c[0][cc]);
            }
            if (t >= 1) {
                #pragma unroll
                for (int kx = 0; kx < 7; ++kx)
                    #pragma unroll
                    for (int cc = 0; cc < 12; ++cc)
                        c[1][cc] = fmaf(wp[kx], row[cc + kx], c[1][cc]);
            }
            #pragma unroll
            for (int i = 0; i < 7; ++i) wp[i] = wc[i];
            if (t < 7) {
                const float* wn = wg + (t + 1) * 7;
                #pragma unroll
                for (int i = 0; i < 7; ++i) wc[i] = wn[i];
            }
        }
        float b = kf_b1[oc];
        #pragma unroll
        for (int j = 0; j < 6; ++j) {
            float m = fmaxf(fmaxf(c[0][2 * j], c[0][2 * j + 1]),
                            fmaxf(c[1][2 * j], c[1][2 * j + 1]));
            sm[OC1 + oc * 132 + py * 12 + 5 * h + j] = fmaxf(m + b, 0.f);
        }
    }
    __syncthreads();

    // ---- conv5 (11->7) partials over ic-halves; c1 rows as float2 ----
    // 180 threads: h5 = ic-half, r5 = (oc,py,px). Each does 4 ic x 100 FMA.
    // h5=0 writes 4 pre-pool partials to p5 (P2 region, dead now); h5=1
    // keeps them in registers across the barrier.
    const int h5 = tid / 90;            // 0,1 (tid<180)
    const int r5 = tid - h5 * 90;       // 0..89
    float a00 = 0.f, a01 = 0.f, a10 = 0.f, a11 = 0.f;
    if (tid < 180) {
        int oc = r5 % 10, rr = r5 / 10;
        int py = rr / 3, px = rr % 3;
        for (int icg = 0; icg < 4; ++icg) {
            int ic = 4 * h5 + icg;
            float w[25];
            const float* wg = kf_w2 + (oc * 8 + ic) * 25;
            #pragma unroll
            for (int i = 0; i < 25; ++i) w[i] = wg[i];
            const float* xb = &sm[OC1 + ic * 132 + 2 * py * 12 + 2 * px];
            float cur[6], nxt[6];
            {
                const float2* xr = (const float2*)xb;
                #pragma unroll
                for (int i = 0; i < 3; ++i) { float2 q = xr[i]; cur[2*i] = q.x; cur[2*i+1] = q.y; }
            }
            #pragma unroll
            for (int ky = 0; ky < 5; ++ky) {
                const float2* xr = (const float2*)(xb + (ky + 1) * 12);
                #pragma unroll
                for (int i = 0; i < 3; ++i) { float2 q = xr[i]; nxt[2*i] = q.x; nxt[2*i+1] = q.y; }
                #pragma unroll
                for (int kx = 0; kx < 5; ++kx) {
                    float wv = w[ky * 5 + kx];
                    a00 = fmaf(wv, cur[kx],     a00);
                    a01 = fmaf(wv, cur[kx + 1], a01);
                    a10 = fmaf(wv, nxt[kx],     a10);
                    a11 = fmaf(wv, nxt[kx + 1], a11);
                }
                #pragma unroll
                for (int i = 0; i < 6; ++i) cur[i] = nxt[i];
            }
        }
        if (h5 == 0) {
            *(float4*)&sm[OP2 + 4 * r5] = float4{a00, a01, a10, a11};
        }
    }
    __syncthreads();

    // ---- conv5 combine (h5=1 threads): sum halves, bias+pool+relu -> f ----
    if (tid >= 90 && tid < 180) {
        int oc = r5 % 10;
        float4 pv = *(const float4*)&sm[OP2 + 4 * r5];
        float m = fmaxf(fmaxf(pv.x + a00, pv.y + a01),
                        fmaxf(pv.z + a10, pv.w + a11)) + kf_b2[oc];
        sm[OF + oc * 9 + (r5 / 10)] = fmaxf(m, 0.f);   // r5/10 = py*3+px
    }
    __syncthreads();

    // ---- fc 90->32 + relu, then fc 32->40: same wave, no barrier ----
    if (tid < 32) {
        float acc = kf_fc1_b[tid];
        const float2* wr = (const float2*)&kf_fc1_w[tid * 90];
        const float2* ff = (const float2*)&sm[OF];
        for (int i = 0; i < 45; ++i) {
            float2 wv = wr[i], fv = ff[i];
            acc = fmaf(wv.x, fv.x, acc);
            acc = fmaf(wv.y, fv.y, acc);
        }
        sm[OH + tid] = fmaxf(acc, 0.f);
    }
    if (tid < 40) {
        float acc = kf_fc2_b[tid];
        const float4* wr = (const float4*)&kf_fc2_w[tid * 32];
        const float4* hh = (const float4*)&sm[OH];
        #pragma unroll
        for (int i = 0; i < 8; ++i) {
            float4 wv = wr[i], hv = hh[i];
            acc = fmaf(wv.x, hv.x, acc);
            acc = fmaf(wv.y, hv.y, acc);
            acc = fmaf(wv.z, hv.z, acc);
            acc = fmaf(wv.w, hv.w, acc);
        }
        sm[OK2 + tid] = acc;
    }
    __syncthreads();

    // ---- dynamic 2x2 conv + pool + relu; 12x12 live region only ----
    if (tid < 120) {
        int oc = tid % 10, py = tid / 10;
        float4 kv = *(const float4*)&sm[OK2 + oc * 4];
        float k0 = kv.x, k1 = kv.y, k2 = kv.z, k3 = kv.w;
        const float* x0 = &sm[OX + 2 * py * 28];
        const float* x1 = x0 + 28;
        const float* x2 = x0 + 56;
        float2 q0 = *(const float2*)&x0[0];
        float2 q1 = *(const float2*)&x1[0];
        float2 q2 = *(const float2*)&x2[0];
        float A0 = q0.x, B0 = q0.y;
        float A1 = q1.x, B1 = q1.y;
        float A2 = q2.x, B2 = q2.y;
        float* yo = &sm[OY + oc * YIC + py * 12];
        #pragma unroll
        for (int j = 0; j < 12; ++j) {
            float2 r0 = *(const float2*)&x0[2 * j + 2];
            float2 r1 = *(const float2*)&x1[2 * j + 2];
            float2 r2v = *(const float2*)&x2[2 * j + 2];
            float C0 = r0.x, C1 = r1.x, C2 = r2v.x;
            float c00 = A0 * k0 + B0 * k1 + A1 * k2 + B1 * k3;
            float c01 = B0 * k0 + C0 * k1 + B1 * k2 + C1 * k3;
            float c10 = A1 * k0 + B1 * k1 + A2 * k2 + B2 * k3;
            float c11 = B1 * k0 + C1 * k1 + B2 * k2 + C2 * k3;
            float m = fmaxf(fmaxf(c00, c01), fmaxf(c10, c11));
            yo[j] = fmaxf(m, 0.f);
            A0 = C0; A1 = C1; A2 = C2;
            B0 = r0.y; B1 = r1.y; B2 = r2v.y;
        }
    }
    __syncthreads();

    // ---- conv2 5x5: 8x8 pooled-live outputs; y rows as 3x float4.
    // h2=0 writes partials to P2; h2=1 keeps acc in regs across barrier.
    const int oc2 = tid % 20;
    const int q2i = tid / 20;
    const int h2  = q2i & 1;
    const int rg2 = q2i >> 1;
    float a2[2][8];
    if (tid < 160) {
        int r0 = 2 * rg2;
        #pragma unroll
        for (int r = 0; r < 2; ++r)
            #pragma unroll
            for (int i = 0; i < 8; ++i) a2[r][i] = 0.f;
        for (int icg = 0; icg < 5; ++icg) {
            int ic = 5 * h2 + icg;
            float w[25];
            const float* wg = conv2_w + (oc2 * 10 + ic) * 25;
            #pragma unroll
            for (int i = 0; i < 25; ++i) w[i] = wg[i];
            const float* yb = &sm[OY + ic * YIC + r0 * 12];
            float row[12];
            #pragma unroll
            for (int u = 0; u < 6; ++u) {
                const float4* ys = (const float4*)(yb + u * 12);
                #pragma unroll
                for (int i = 0; i < 3; ++i) {
                    float4 q = ys[i];
                    row[4*i] = q.x; row[4*i+1] = q.y; row[4*i+2] = q.z; row[4*i+3] = q.w;
                }
                #pragma unroll
                for (int rr = 0; rr < 2; ++rr) {
                    int ky = u - rr;
                    if (ky >= 0 && ky <= 4) {
                        #pragma unroll
                        for (int kx = 0; kx < 5; ++kx)
                            #pragma unroll
                            for (int cx = 0; cx < 8; ++cx)
                                a2[rr][cx] = fmaf(w[ky * 5 + kx], row[cx + kx], a2[rr][cx]);
                    }
                }
            }
        }
        if (h2 == 0) {
            int r0w = 2 * rg2;
            #pragma unroll
            for (int rr = 0; rr < 2; ++rr)
                #pragma unroll
                for (int cx = 0; cx < 8; ++cx)
                    sm[OP2 + oc2 * 65 + (r0w + rr) * 8 + cx] = a2[rr][cx];
        }
    }
    __syncthreads();

    // ---- combine halves + bias + pool + relu -> p3[20,4,4] ----
    if (tid < 160 && h2 == 1) {
        float b = conv2_b[oc2];
        const float* p0 = &sm[OP2 + oc2 * 65 + (2 * rg2) * 8];
        #pragma unroll
        for (int px = 0; px < 4; ++px) {
            float c00 = b + a2[0][2 * px]     + p0[2 * px];
            float c01 = b + a2[0][2 * px + 1] + p0[2 * px + 1];
            float c10 = b + a2[1][2 * px]     + p0[8 + 2 * px];
            float c11 = b + a2[1][2 * px + 1] + p0[8 + 2 * px + 1];
            float m = fmaxf(fmaxf(c00, c01), fmaxf(c10, c11));
            sm[OP3 + oc2 * 16 + rg2 * 4 + px] = fmaxf(m, 0.f);
        }
    }
    __syncthreads();

    // ---- fc 320->50, 2-way k-split (100 threads, 40 float4 each) ----
    if (tid < 100) {
        int g = tid / 50, o = tid % 50;
        const float4* wr4 = (const float4*)&fc1_w[o * 320 + g * 160];
        const float4* pp4 = (const float4*)&sm[OP3 + g * 160];
        float acc = 0.f;
        for (int i = 0; i < 40; ++i) {
            float4 wv = wr4[i], pv = pp4[i];
            acc = fmaf(wv.x, pv.x, acc);
            acc = fmaf(wv.y, pv.y, acc);
            acc = fmaf(wv.z, pv.z, acc);
            acc = fmaf(wv.w, pv.w, acc);
        }
        sm[OPF + tid] = acc;
    }
    __syncthreads();

    // ---- tail: wave 0, barrier-free (intra-wave LDS ordering) ----
    if (tid < 50) {
        float acc = fc1_b[tid] + sm[OPF + tid] + sm[OPF + 50 + tid];
        sm[OA1 + tid] = fmaxf(acc, 0.f);
    }
    if (tid < 10) {
        float acc = fc2_b[tid];
        const float2* wr = (const float2*)&fc2_w[tid * 50];
        #pragma unroll
        for (int i = 0; i < 25; ++i) {
            float2 wv = wr[i];
            acc = fmaf(wv.x, sm[OA1 + 2 * i], acc);
            acc = fmaf(wv.y, sm[OA1 + 2 * i + 1], acc);
        }
        sm[OZ + tid] = acc;
    }
    if (tid < 10) {
        float m = sm[OZ + 0];
        #pragma unroll
        for (int i = 1; i < 10; ++i) m = fmaxf(m, sm[OZ + i]);
        float s = 0.f;
        #pragma unroll
        for (int i = 0; i < 10; ++i) s += expf(sm[OZ + i] - m);
        out[n * 10 + tid] = sm[OZ + tid] - m - logf(s);
    }
}

extern "C" void kernel_launch(void* const* d_in, const int* in_sizes, int n_in,
                              void* d_out, int out_size, void* d_ws, size_t ws_size,
                              hipStream_t stream) {
    const float* x        = (const float*)d_in[0];
    const float* kf_w1    = (const float*)d_in[1];
    const float* kf_b1    = (const float*)d_in[2];
    const float* kf_w2    = (const float*)d_in[3];
    const float* kf_b2    = (const float*)d_in[4];
    const float* kf_fc1_w = (const float*)d_in[5];
    const float* kf_fc1_b = (const float*)d_in[6];
    const float* kf_fc2_w = (const float*)d_in[7];
    const float* kf_fc2_b = (const float*)d_in[8];
    const float* conv2_w  = (const float*)d_in[9];
    const float* conv2_b  = (const float*)d_in[10];
    const float* fc1_w    = (const float*)d_in[11];
    const float* fc1_b    = (const float*)d_in[12];
    const float* fc2_w    = (const float*)d_in[13];
    const float* fc2_b    = (const float*)d_in[14];

    const int N = in_sizes[0] / 784;   // 8192

    fused_forward<<<N, TPB, 0, stream>>>(
        x, kf_w1, kf_b1, kf_w2, kf_b2, kf_fc1_w, kf_fc1_b, kf_fc2_w, kf_fc2_b,
        conv2_w, conv2_b, fc1_w, fc1_b, fc2_w, fc2_b, (float*)d_out);
}

// Round 11
// 250.662 us; speedup vs baseline: 1.5345x; 1.1244x over previous
//
#include <hip/hip_runtime.h>
#include <math.h>

#define TPB 192

typedef __attribute__((ext_vector_type(8))) short bf16x8;
typedef __attribute__((ext_vector_type(4))) float f32x4;

// ---- LDS layout (float offsets), lifetime-overlaid. ----
// x   [0,784)       staged input; dead after dyn
// c1  [784,1840)    conv7 out [8][11][12]; dead after conv5
// y2  [784,2656)    dyn out, bf16 [13 row][12 col][24 ic-pad] (3744 bf16 =
//                   1872 f). Overlays dead c1; zeroed during fc phase by
//                   waves 1-2 (pads: ic>=10, row 12). Row stride 288 bf16
//                   (=576B, bank-spread), col stride 24 (48B, 16B-aligned
//                   b128 reads, banks spread).
// f   [2656,2746)   conv5 out (in future-C region; dead before MFMA)
// h   [2748,2780)   fc1 out   (same)
// C   [2656,4960)   conv2 MFMA out [64 n][36 oc-pad] f32 (stride 36: 16B-
//                   aligned b128 writes, 2-way banks = free)
// k   [4960,5000)   dyn kernels
// p3 [0,320) pf [320,420) a1 [420,470) z [472,482)  (over dead x)
#define OX    0
#define OC1   784
#define OY2   784
#define OF    2656
#define OH    2748
#define OC2S  2656
#define OK2   4960
#define OP3   0
#define OPF   320
#define OA1   420
#define OZ    472
#define SM_TOT 5000   // 20000 B -> 8 blocks/CU LDS cap (wave cap 10)

// Packed conv2 weights in d_ws: bf16 W3[5 kx][3 kyp][32 oc][32 k],
// k = kyip*16 + ic (ky = 2*kyp + kyip; oc>=20 / ic>=10 / ky>=5 -> 0).
// 15360 bf16 = 30720 B (ws >= 33408 B confirmed in R5).
#define W3_ENTRIES 15360

__device__ __forceinline__ unsigned short f2bf(float f) {
    unsigned int u = __float_as_uint(f);
    u += 0x7FFF + ((u >> 16) & 1);          // round-to-nearest-even
    return (unsigned short)(u >> 16);
}

__global__ void repack_w3(const float* __restrict__ conv2_w,
                          unsigned short* __restrict__ w3)
{
    int i = blockIdx.x * blockDim.x + threadIdx.x;
    if (i >= W3_ENTRIES) return;
    int k  = i & 31;
    int oc = (i >> 5) & 31;
    int g  = i >> 10;            // kx*3 + kyp, 0..14
    int kyp = g % 3, kx = g / 3;
    int kyip = k >> 4, ic = k & 15, ky = 2 * kyp + kyip;
    float v = 0.f;
    if (oc < 20 && ic < 10 && ky < 5)
        v = conv2_w[(oc * 10 + ic) * 25 + ky * 5 + kx];
    w3[i] = f2bf(v);
}

// R11: conv2 -> MFMA. The kernel is issue-bound (R8/R10 calibration): conv2
// was 6000 of ~12K wave-FMA/block. Now: 120 x mfma_f32_16x16x32_bf16 over
// 2 waves x 4 tiles (waves own disjoint n-ranges -> no partial sums).
// A-frag = 16B global load from W3; B-frag = ds_read_b128 from y2 (written
// bf16 by dyn). K=32 packs 2 ky taps x 16 ic-pad -> 15 k-steps. Fragment
// layouts: A row=l&15 k=(l>>4)*8+e; B col=l&15; C col=l&15 row=(l>>4)*4+reg.
// bf16 error est ~2e-4 final (K=250, terms ~5e-3) vs 0.0156 margin.
// Everything pre-dyn is byte-identical to R6 (scalar weight loads; no
// forced rolling; LDS-vectorized reads).
__global__ __launch_bounds__(TPB) void fused_forward(
    const float* __restrict__ x,
    const float* __restrict__ kf_w1, const float* __restrict__ kf_b1,
    const float* __restrict__ kf_w2, const float* __restrict__ kf_b2,
    const float* __restrict__ kf_fc1_w, const float* __restrict__ kf_fc1_b,
    const float* __restrict__ kf_fc2_w, const float* __restrict__ kf_fc2_b,
    const float* __restrict__ conv2_w, const float* __restrict__ conv2_b,
    const float* __restrict__ fc1_w, const float* __restrict__ fc1_b,
    const float* __restrict__ fc2_w, const float* __restrict__ fc2_b,
    const unsigned short* __restrict__ w3,
    float* __restrict__ out)
{
    __shared__ __align__(16) float sm[SM_TOT];
    const int tid = threadIdx.x;
    const int n = blockIdx.x;

    // ---- stage 0: stage x into LDS (float4) ----
    {
        const float4* xg = (const float4*)(x + (long long)n * 784);
        float4* d = (float4*)&sm[OX];
        for (int i = tid; i < 196; i += TPB) d[i] = xg[i];
    }
    __syncthreads();

    // ---- conv7 (28->22) + pool (->11) + relu ----
    if (tid < 176) {
        int oc = tid & 7;
        int r  = tid >> 3;
        int py = r >> 1;
        int h  = r & 1;
        const int cc0 = 10 * h;
        float c[2][12];
        #pragma unroll
        for (int r2 = 0; r2 < 2; ++r2)
            #pragma unroll
            for (int i = 0; i < 12; ++i) c[r2][i] = 0.f;
        float wc[7], wp[7];
        const float* wg = kf_w1 + oc * 49;
        #pragma unroll
        for (int i = 0; i < 7; ++i) wc[i] = wg[i];
        #pragma unroll
        for (int t = 0; t < 8; ++t) {
            const float2* xs = (const float2*)&sm[OX + (2 * py + t) * 28 + cc0];
            float row[18];
            #pragma unroll
            for (int i = 0; i < 9; ++i) { float2 q = xs[i]; row[2*i] = q.x; row[2*i+1] = q.y; }
            if (t <= 6) {
                #pragma unroll
                for (int kx = 0; kx < 7; ++kx)
                    #pragma unroll
                    for (int cc = 0; cc < 12; ++cc)
                        c[0][cc] = fmaf(wc[kx], row[cc + kx], c[0][cc]);
            }
            if (t >= 1) {
                #pragma unroll
                for (int kx = 0; kx < 7; ++kx)
                    #pragma unroll
                    for (int cc = 0; cc < 12; ++cc)
                        c[1][cc] = fmaf(wp[kx], row[cc + kx], c[1][cc]);
            }
            #pragma unroll
            for (int i = 0; i < 7; ++i) wp[i] = wc[i];
            if (t < 7) {
                const float* wn = wg + (t + 1) * 7;
                #pragma unroll
                for (int i = 0; i < 7; ++i) wc[i] = wn[i];
            }
        }
        float b = kf_b1[oc];
        #pragma unroll
        for (int j = 0; j < 6; ++j) {
            float m = fmaxf(fmaxf(c[0][2 * j], c[0][2 * j + 1]),
                            fmaxf(c[1][2 * j], c[1][2 * j + 1]));
            sm[OC1 + oc * 132 + py * 12 + 5 * h + j] = fmaxf(m + b, 0.f);
        }
    }
    __syncthreads();

    // ---- conv5 (11->7) + pool (->3) + relu; c1 rows as float2 ----
    if (tid < 90) {
        int oc = tid % 10, r = tid / 10;
        int py = r / 3, px = r % 3;
        float a00 = 0.f, a01 = 0.f, a10 = 0.f, a11 = 0.f;
        for (int ic = 0; ic < 8; ++ic) {
            float w[25];
            const float* wg = kf_w2 + (oc * 8 + ic) * 25;
            #pragma unroll
            for (int i = 0; i < 25; ++i) w[i] = wg[i];
            const float* xb = &sm[OC1 + ic * 132 + 2 * py * 12 + 2 * px];
            float cur[6], nxt[6];
            {
                const float2* xr = (const float2*)xb;
                #pragma unroll
                for (int i = 0; i < 3; ++i) { float2 q = xr[i]; cur[2*i] = q.x; cur[2*i+1] = q.y; }
            }
            #pragma unroll
            for (int ky = 0; ky < 5; ++ky) {
                const float2* xr = (const float2*)(xb + (ky + 1) * 12);
                #pragma unroll
                for (int i = 0; i < 3; ++i) { float2 q = xr[i]; nxt[2*i] = q.x; nxt[2*i+1] = q.y; }
                #pragma unroll
                for (int kx = 0; kx < 5; ++kx) {
                    float wv = w[ky * 5 + kx];
                    a00 = fmaf(wv, cur[kx],     a00);
                    a01 = fmaf(wv, cur[kx + 1], a01);
                    a10 = fmaf(wv, nxt[kx],     a10);
                    a11 = fmaf(wv, nxt[kx + 1], a11);
                }
                #pragma unroll
                for (int i = 0; i < 6; ++i) cur[i] = nxt[i];
            }
        }
        float m = fmaxf(fmaxf(a00, a01), fmaxf(a10, a11)) + kf_b2[oc];
        sm[OF + oc * 9 + py * 3 + px] = fmaxf(m, 0.f);
    }
    __syncthreads();

    // ---- wave 0: fc 90->32 + relu, fc 32->40 (no barrier between);
    //      waves 1-2: zero y2 (disjoint region; c1 dead) ----
    if (tid < 32) {
        float acc = kf_fc1_b[tid];
        const float2* wr = (const float2*)&kf_fc1_w[tid * 90];
        const float2* ff = (const float2*)&sm[OF];
        for (int i = 0; i < 45; ++i) {
            float2 wv = wr[i], fv = ff[i];
            acc = fmaf(wv.x, fv.x, acc);
            acc = fmaf(wv.y, fv.y, acc);
        }
        sm[OH + tid] = fmaxf(acc, 0.f);
    }
    if (tid < 40) {
        float acc = kf_fc2_b[tid];
        const float4* wr = (const float4*)&kf_fc2_w[tid * 32];
        const float4* hh = (const float4*)&sm[OH];
        #pragma unroll
        for (int i = 0; i < 8; ++i) {
            float4 wv = wr[i], hv = hh[i];
            acc = fmaf(wv.x, hv.x, acc);
            acc = fmaf(wv.y, hv.y, acc);
            acc = fmaf(wv.z, hv.z, acc);
            acc = fmaf(wv.w, hv.w, acc);
        }
        sm[OK2 + tid] = acc;
    }
    if (tid >= 64) {
        float4* z4 = (float4*)&sm[OY2];          // 1872 floats = 468 float4
        for (int i = tid - 64; i < 468; i += 128) z4[i] = float4{0.f, 0.f, 0.f, 0.f};
    }
    __syncthreads();

    // ---- dynamic 2x2 conv + pool + relu -> y2 bf16 [row][col][ic] ----
    if (tid < 120) {
        int oc = tid % 10, py = tid / 10;      // py 0..11
        float4 kv = *(const float4*)&sm[OK2 + oc * 4];
        float k0 = kv.x, k1 = kv.y, k2 = kv.z, k3 = kv.w;
        const float* x0 = &sm[OX + 2 * py * 28];
        const float* x1 = x0 + 28;
        const float* x2 = x0 + 56;
        float2 q0 = *(const float2*)&x0[0];
        float2 q1 = *(const float2*)&x1[0];
        float2 q2 = *(const float2*)&x2[0];
        float A0 = q0.x, B0 = q0.y;
        float A1 = q1.x, B1 = q1.y;
        float A2 = q2.x, B2 = q2.y;
        unsigned short* y2 = (unsigned short*)&sm[OY2];
        #pragma unroll
        for (int j = 0; j < 12; ++j) {
            float2 r0 = *(const float2*)&x0[2 * j + 2];
            float2 r1 = *(const float2*)&x1[2 * j + 2];
            float2 r2v = *(const float2*)&x2[2 * j + 2];
            float C0 = r0.x, C1 = r1.x, C2 = r2v.x;
            float c00 = A0 * k0 + B0 * k1 + A1 * k2 + B1 * k3;
            float c01 = B0 * k0 + C0 * k1 + B1 * k2 + C1 * k3;
            float c10 = A1 * k0 + B1 * k1 + A2 * k2 + B2 * k3;
            float c11 = B1 * k0 + C1 * k1 + B2 * k2 + C2 * k3;
            float m = fmaxf(fmaxf(c00, c01), fmaxf(c10, c11));
            y2[py * 288 + j * 24 + oc] = f2bf(fmaxf(m, 0.f));
            A0 = C0; A1 = C1; A2 = C2;
            B0 = r0.y; B1 = r1.y; B2 = r2v.y;
        }
    }
    __syncthreads();

    // ---- conv2 via MFMA: 2 waves x {2 M-tiles x 2 N-tiles}; 15 k-steps ----
    {
        const int wv = tid >> 6;
        if (wv < 2) {
            const int l  = tid & 63;
            const int lm = l & 15, lk = l >> 4;
            f32x4 a00 = {0.f, 0.f, 0.f, 0.f};
            f32x4 a01 = a00, a10 = a00, a11 = a00;
            const char* W3 = (const char*)w3;
            const int aoff = (lm * 32 + lk * 8) * 2;       // bytes within 2KB step blk
            const int n0 = wv * 32 + lm;                   // output positions
            const int n1 = n0 + 16;
            const int kyip = l >> 5, icb = (lk & 1) * 8;
            const unsigned short* Y2 = (const unsigned short*)&sm[OY2];
            const int b0 = ((n0 >> 3) + kyip) * 288 + (n0 & 7) * 24 + icb;
            const int b1 = ((n1 >> 3) + kyip) * 288 + (n1 & 7) * 24 + icb;
            #pragma unroll
            for (int p = 0; p < 3; ++p) {
                #pragma unroll
                for (int kx = 0; kx < 5; ++kx) {
                    const char* wa = W3 + (kx * 3 + p) * 2048 + aoff;
                    bf16x8 A0 = *(const bf16x8*)wa;
                    bf16x8 A1 = *(const bf16x8*)(wa + 1024);
                    const int bo = p * 576 + kx * 24;      // bf16 units
                    bf16x8 B0 = *(const bf16x8*)(Y2 + b0 + bo);
                    bf16x8 B1 = *(const bf16x8*)(Y2 + b1 + bo);
                    a00 = __builtin_amdgcn_mfma_f32_16x16x32_bf16(A0, B0, a00, 0, 0, 0);
                    a01 = __builtin_amdgcn_mfma_f32_16x16x32_bf16(A0, B1, a01, 0, 0, 0);
                    a10 = __builtin_amdgcn_mfma_f32_16x16x32_bf16(A1, B0, a10, 0, 0, 0);
                    a11 = __builtin_amdgcn_mfma_f32_16x16x32_bf16(A1, B1, a11, 0, 0, 0);
                }
            }
            float* C = &sm[OC2S];
            *(f32x4*)(C + n0 * 36 + lk * 4)      = a00;    // oc 0..15
            *(f32x4*)(C + n1 * 36 + lk * 4)      = a01;
            *(f32x4*)(C + n0 * 36 + 16 + lk * 4) = a10;    // oc 16..31 (20+ pad)
            *(f32x4*)(C + n1 * 36 + 16 + lk * 4) = a11;
        }
    }
    __syncthreads();

    // ---- pool C[64][36] + bias + relu -> p3[20,4,4] (80 threads) ----
    if (tid < 80) {
        int oc = tid % 20, py = tid / 20;      // py 0..3
        float b = conv2_b[oc];
        const float* C = &sm[OC2S];
        #pragma unroll
        for (int px = 0; px < 4; ++px) {
            int n00 = (2 * py) * 8 + 2 * px;
            float c00 = C[n00 * 36 + oc];
            float c01 = C[(n00 + 1) * 36 + oc];
            float c10 = C[(n00 + 8) * 36 + oc];
            float c11 = C[(n00 + 9) * 36 + oc];
            float m = fmaxf(fmaxf(c00, c01), fmaxf(c10, c11)) + b;
            sm[OP3 + oc * 16 + py * 4 + px] = fmaxf(m, 0.f);
        }
    }
    __syncthreads();

    // ---- fc 320->50, 2-way k-split (100 threads, 40 float4 each) ----
    if (tid < 100) {
        int g = tid / 50, o = tid % 50;
        const float4* wr4 = (const float4*)&fc1_w[o * 320 + g * 160];
        const float4* pp4 = (const float4*)&sm[OP3 + g * 160];
        float acc = 0.f;
        for (int i = 0; i < 40; ++i) {
            float4 wv = wr4[i], pv = pp4[i];
            acc = fmaf(wv.x, pv.x, acc);
            acc = fmaf(wv.y, pv.y, acc);
            acc = fmaf(wv.z, pv.z, acc);
            acc = fmaf(wv.w, pv.w, acc);
        }
        sm[OPF + tid] = acc;
    }
    __syncthreads();

    // ---- tail: wave 0, barrier-free (intra-wave LDS ordering) ----
    if (tid < 50) {
        float acc = fc1_b[tid] + sm[OPF + tid] + sm[OPF + 50 + tid];
        sm[OA1 + tid] = fmaxf(acc, 0.f);
    }
    if (tid < 10) {
        float acc = fc2_b[tid];
        const float2* wr = (const float2*)&fc2_w[tid * 50];
        #pragma unroll
        for (int i = 0; i < 25; ++i) {
            float2 wv = wr[i];
            acc = fmaf(wv.x, sm[OA1 + 2 * i], acc);
            acc = fmaf(wv.y, sm[OA1 + 2 * i + 1], acc);
        }
        sm[OZ + tid] = acc;
    }
    if (tid < 10) {
        float m = sm[OZ + 0];
        #pragma unroll
        for (int i = 1; i < 10; ++i) m = fmaxf(m, sm[OZ + i]);
        float s = 0.f;
        #pragma unroll
        for (int i = 0; i < 10; ++i) s += expf(sm[OZ + i] - m);
        out[n * 10 + tid] = sm[OZ + tid] - m - logf(s);
    }
}

extern "C" void kernel_launch(void* const* d_in, const int* in_sizes, int n_in,
                              void* d_out, int out_size, void* d_ws, size_t ws_size,
                              hipStream_t stream) {
    const float* x        = (const float*)d_in[0];
    const float* kf_w1    = (const float*)d_in[1];
    const float* kf_b1    = (const float*)d_in[2];
    const float* kf_w2    = (const float*)d_in[3];
    const float* kf_b2    = (const float*)d_in[4];
    const float* kf_fc1_w = (const float*)d_in[5];
    const float* kf_fc1_b = (const float*)d_in[6];
    const float* kf_fc2_w = (const float*)d_in[7];
    const float* kf_fc2_b = (const float*)d_in[8];
    const float* conv2_w  = (const float*)d_in[9];
    const float* conv2_b  = (const float*)d_in[10];
    const float* fc1_w    = (const float*)d_in[11];
    const float* fc1_b    = (const float*)d_in[12];
    const float* fc2_w    = (const float*)d_in[13];
    const float* fc2_b    = (const float*)d_in[14];

    const int N = in_sizes[0] / 784;   // 8192

    unsigned short* w3 = (unsigned short*)d_ws;   // 30720 B (ws >= 33 KB, R5)
    repack_w3<<<(W3_ENTRIES + 255) / 256, 256, 0, stream>>>(conv2_w, w3);

    fused_forward<<<N, TPB, 0, stream>>>(
        x, kf_w1, kf_b1, kf_w2, kf_b2, kf_fc1_w, kf_fc1_b, kf_fc2_w, kf_fc2_b,
        conv2_w, conv2_b, fc1_w, fc1_b, fc2_w, fc2_b, w3, (float*)d_out);
}

// Round 12
// 230.510 us; speedup vs baseline: 1.6686x; 1.0874x over previous
//
#include <hip/hip_runtime.h>
#include <math.h>

#define TPB 192

typedef __attribute__((ext_vector_type(8))) short bf16x8;
typedef __attribute__((ext_vector_type(4))) float f32x4;

// ---- LDS layout (float offsets), lifetime-overlaid. ----
// x    [0,784)      staged input; dead after dyn
// c1b  [784,1312)   conv7 out bf16 [11 row][12 col][8 ic] (cell = 16B ->
//                   aligned b128 B-frags for conv5 MFMA); dead after conv5
// C5   [1312,2272)  conv5 MFMA out f32 [48 n][20 oc-pad] (stride 20 -> 2-way
//                   banks); dead after pool
// y2   [784,2656)   dyn out bf16 [13 row][12 col][24 ic-pad]; overlays dead
//                   c1b/C5; zeroed during fc phase by waves 1-2
// f    [2656,2746)  conv5 pooled out (in dead-C region, outside y2-zero!)
// h    [2748,2780)  fc1 out (same)
// C    [2656,4960)  conv2 MFMA out [64 n][36 oc-pad] f32
// k    [4960,5000)  dyn kernels
// p3 [0,320) pf [320,420) a1 [420,470) z [472,482)  (over dead x)
#define OX    0
#define OC1B  784
#define OC5   1312
#define OY2   784
#define OF    2656
#define OH    2748
#define OC2S  2656
#define OK2   4960
#define OP3   0
#define OPF   320
#define OA1   420
#define OZ    472
#define SM_TOT 5000   // 20000 B (unchanged from R11)

// Packed weights in d_ws (ushort units):
// W3 [5 kx][3 kyp][20 oc][32 k] @ 0      (9600)  — conv2 A; k = kyip*16+ic
// W5 [7 s][16 oc][32 k]        @ 9600   (3584)  — conv5 A; k = tap_loc*8+ic,
//                                         tap = 4s+tap_loc, (ky,kx)=(t/5,t%5)
#define W3U 0
#define W5U 9600
#define WSU_TOT 13184   // 26368 B <= 33408 (R5-verified ws floor)

__device__ __forceinline__ unsigned short f2bf(float f) {
    unsigned int u = __float_as_uint(f);
    u += 0x7FFF + ((u >> 16) & 1);          // round-to-nearest-even
    return (unsigned short)(u >> 16);
}

__global__ void repack_w(const float* __restrict__ conv2_w,
                         const float* __restrict__ kf_w2,
                         unsigned short* __restrict__ ws)
{
    int i = blockIdx.x * blockDim.x + threadIdx.x;
    if (i < 9600) {            // W3
        int g = i / 640, rem = i % 640;
        int oc = rem >> 5, k = rem & 31;
        int kyp = g % 3, kx = g / 3;
        int kyip = k >> 4, ic = k & 15, ky = 2 * kyp + kyip;
        float v = 0.f;
        if (ic < 10 && ky < 5)
            v = conv2_w[(oc * 10 + ic) * 25 + ky * 5 + kx];
        ws[W3U + i] = f2bf(v);
    } else if (i < WSU_TOT) {  // W5
        int j = i - 9600;
        int s = j >> 9, rem = j & 511;
        int oc = rem >> 5, k = rem & 31;
        int tap = 4 * s + (k >> 3), ic = k & 7;
        float v = 0.f;
        if (oc < 10 && tap < 25)
            v = kf_w2[(oc * 8 + ic) * 25 + tap];
        ws[W5U + j] = f2bf(v);
    }
}

// R12: conv5 -> MFMA (same lever as R11's conv2 win: kernel is issue-bound,
// only instruction-stream cuts have ever helped). c1 stored [row][col][8 ic]
// bf16 -> B-frag = one aligned ds_read_b128 per k-step (no im2col). 3 waves
// x 7 MFMA over pre-pool 6x6 C, then 90-thread pool. W3 shrunk 32->20 oc
// rows (A1 lanes clamp oc=min(16+lm,19); garbage C rows 20-31 unused) to
// fit W5 in ws. Everything else byte-identical to R11.
__global__ __launch_bounds__(TPB) void fused_forward(
    const float* __restrict__ x,
    const float* __restrict__ kf_w1, const float* __restrict__ kf_b1,
    const float* __restrict__ kf_w2, const float* __restrict__ kf_b2,
    const float* __restrict__ kf_fc1_w, const float* __restrict__ kf_fc1_b,
    const float* __restrict__ kf_fc2_w, const float* __restrict__ kf_fc2_b,
    const float* __restrict__ conv2_w, const float* __restrict__ conv2_b,
    const float* __restrict__ fc1_w, const float* __restrict__ fc1_b,
    const float* __restrict__ fc2_w, const float* __restrict__ fc2_b,
    const unsigned short* __restrict__ wsu,
    float* __restrict__ out)
{
    __shared__ __align__(16) float sm[SM_TOT];
    const int tid = threadIdx.x;
    const int n = blockIdx.x;

    // ---- stage 0: stage x into LDS (float4) ----
    {
        const float4* xg = (const float4*)(x + (long long)n * 784);
        float4* d = (float4*)&sm[OX];
        for (int i = tid; i < 196; i += TPB) d[i] = xg[i];
    }
    __syncthreads();

    // ---- conv7 (28->22) + pool (->11) + relu -> c1b bf16 [row][col][ic] ----
    if (tid < 176) {
        int oc = tid & 7;
        int r  = tid >> 3;
        int py = r >> 1;
        int h  = r & 1;
        const int cc0 = 10 * h;
        float c[2][12];
        #pragma unroll
        for (int r2 = 0; r2 < 2; ++r2)
            #pragma unroll
            for (int i = 0; i < 12; ++i) c[r2][i] = 0.f;
        float wc[7], wp[7];
        const float* wg = kf_w1 + oc * 49;
        #pragma unroll
        for (int i = 0; i < 7; ++i) wc[i] = wg[i];
        #pragma unroll
        for (int t = 0; t < 8; ++t) {
            const float2* xs = (const float2*)&sm[OX + (2 * py + t) * 28 + cc0];
            float row[18];
            #pragma unroll
            for (int i = 0; i < 9; ++i) { float2 q = xs[i]; row[2*i] = q.x; row[2*i+1] = q.y; }
            if (t <= 6) {
                #pragma unroll
                for (int kx = 0; kx < 7; ++kx)
                    #pragma unroll
                    for (int cc = 0; cc < 12; ++cc)
                        c[0][cc] = fmaf(wc[kx], row[cc + kx], c[0][cc]);
            }
            if (t >= 1) {
                #pragma unroll
                for (int kx = 0; kx < 7; ++kx)
                    #pragma unroll
                    for (int cc = 0; cc < 12; ++cc)
                        c[1][cc] = fmaf(wp[kx], row[cc + kx], c[1][cc]);
            }
            #pragma unroll
            for (int i = 0; i < 7; ++i) wp[i] = wc[i];
            if (t < 7) {
                const float* wn = wg + (t + 1) * 7;
                #pragma unroll
                for (int i = 0; i < 7; ++i) wc[i] = wn[i];
            }
        }
        float b = kf_b1[oc];
        unsigned short* c1b = (unsigned short*)&sm[OC1B];
        #pragma unroll
        for (int j = 0; j < 6; ++j) {
            float m = fmaxf(fmaxf(c[0][2 * j], c[0][2 * j + 1]),
                            fmaxf(c[1][2 * j], c[1][2 * j + 1]));
            c1b[py * 96 + (5 * h + j) * 8 + oc] = f2bf(fmaxf(m + b, 0.f));
        }
    }
    __syncthreads();

    // ---- conv5 via MFMA: 3 waves x 1 N-tile x 7 k-steps -> C5[48][20] ----
    {
        const int wv = tid >> 6, l = tid & 63;
        const int lm = l & 15, lq = l >> 4;
        int nn = wv * 16 + lm;
        int nc = nn > 35 ? 35 : nn;            // clamp pad lanes (garbage ok)
        const int rr = nc / 6, cc = nc - rr * 6;
        const unsigned short* c1b = (const unsigned short*)&sm[OC1B];
        const char* W5 = (const char*)(wsu + W5U);
        f32x4 acc = {0.f, 0.f, 0.f, 0.f};
        #pragma unroll
        for (int s = 0; s < 7; ++s) {
            int tap = 4 * s + lq;
            int ky = (tap * 13) >> 6;          // tap/5 for tap<=27
            int kx = tap - ky * 5;
            bf16x8 A = *(const bf16x8*)(W5 + s * 1024 + lm * 64 + lq * 16);
            bf16x8 B = *(const bf16x8*)(c1b + (rr + ky) * 96 + (cc + kx) * 8);
            acc = __builtin_amdgcn_mfma_f32_16x16x32_bf16(A, B, acc, 0, 0, 0);
        }
        // C/D: col = lm (n), row(oc) = lq*4 + reg
        *(f32x4*)(&sm[OC5] + nn * 20 + lq * 4) = acc;
    }
    __syncthreads();

    // ---- conv5 pool: C5 pre-pool 6x6 -> f[10][9] + bias + relu ----
    if (tid < 90) {
        int oc = tid % 10, rr = tid / 10;      // rr = py*3+px
        int py = rr / 3, px = rr % 3;
        const float* C5 = &sm[OC5];
        int nb = (2 * py) * 6 + 2 * px;
        float v = fmaxf(fmaxf(C5[nb * 20 + oc], C5[(nb + 1) * 20 + oc]),
                        fmaxf(C5[(nb + 6) * 20 + oc], C5[(nb + 7) * 20 + oc]));
        sm[OF + oc * 9 + rr] = fmaxf(v + kf_b2[oc], 0.f);
    }
    __syncthreads();

    // ---- wave 0: fc 90->32 + relu, fc 32->40 (no barrier between);
    //      waves 1-2: zero y2 (f/h live at 2656+, outside the zero range) ----
    if (tid < 32) {
        float acc = kf_fc1_b[tid];
        const float2* wr = (const float2*)&kf_fc1_w[tid * 90];
        const float2* ff = (const float2*)&sm[OF];
        for (int i = 0; i < 45; ++i) {
            float2 wv = wr[i], fv = ff[i];
            acc = fmaf(wv.x, fv.x, acc);
            acc = fmaf(wv.y, fv.y, acc);
        }
        sm[OH + tid] = fmaxf(acc, 0.f);
    }
    if (tid < 40) {
        float acc = kf_fc2_b[tid];
        const float4* wr = (const float4*)&kf_fc2_w[tid * 32];
        const float4* hh = (const float4*)&sm[OH];
        #pragma unroll
        for (int i = 0; i < 8; ++i) {
            float4 wv = wr[i], hv = hh[i];
            acc = fmaf(wv.x, hv.x, acc);
            acc = fmaf(wv.y, hv.y, acc);
            acc = fmaf(wv.z, hv.z, acc);
            acc = fmaf(wv.w, hv.w, acc);
        }
        sm[OK2 + tid] = acc;
    }
    if (tid >= 64) {
        float4* z4 = (float4*)&sm[OY2];          // 1872 floats = 468 float4
        for (int i = tid - 64; i < 468; i += 128) z4[i] = float4{0.f, 0.f, 0.f, 0.f};
    }
    __syncthreads();

    // ---- dynamic 2x2 conv + pool + relu -> y2 bf16 [row][col][ic] ----
    if (tid < 120) {
        int oc = tid % 10, py = tid / 10;      // py 0..11
        float4 kv = *(const float4*)&sm[OK2 + oc * 4];
        float k0 = kv.x, k1 = kv.y, k2 = kv.z, k3 = kv.w;
        const float* x0 = &sm[OX + 2 * py * 28];
        const float* x1 = x0 + 28;
        const float* x2 = x0 + 56;
        float2 q0 = *(const float2*)&x0[0];
        float2 q1 = *(const float2*)&x1[0];
        float2 q2 = *(const float2*)&x2[0];
        float A0 = q0.x, B0 = q0.y;
        float A1 = q1.x, B1 = q1.y;
        float A2 = q2.x, B2 = q2.y;
        unsigned short* y2 = (unsigned short*)&sm[OY2];
        #pragma unroll
        for (int j = 0; j < 12; ++j) {
            float2 r0 = *(const float2*)&x0[2 * j + 2];
            float2 r1 = *(const float2*)&x1[2 * j + 2];
            float2 r2v = *(const float2*)&x2[2 * j + 2];
            float C0 = r0.x, C1 = r1.x, C2 = r2v.x;
            float c00 = A0 * k0 + B0 * k1 + A1 * k2 + B1 * k3;
            float c01 = B0 * k0 + C0 * k1 + B1 * k2 + C1 * k3;
            float c10 = A1 * k0 + B1 * k1 + A2 * k2 + B2 * k3;
            float c11 = B1 * k0 + C1 * k1 + B2 * k2 + C2 * k3;
            float m = fmaxf(fmaxf(c00, c01), fmaxf(c10, c11));
            y2[py * 288 + j * 24 + oc] = f2bf(fmaxf(m, 0.f));
            A0 = C0; A1 = C1; A2 = C2;
            B0 = r0.y; B1 = r1.y; B2 = r2v.y;
        }
    }
    __syncthreads();

    // ---- conv2 via MFMA: 2 waves x {2 M x 2 N tiles}; 15 k-steps ----
    {
        const int wv = tid >> 6;
        if (wv < 2) {
            const int l  = tid & 63;
            const int lm = l & 15, lk = l >> 4;
            f32x4 a00 = {0.f, 0.f, 0.f, 0.f};
            f32x4 a01 = a00, a10 = a00, a11 = a00;
            const char* W3 = (const char*)(wsu + W3U);
            const int aoff0 = lm * 64 + lk * 16;
            const int oc1 = 16 + (lm < 4 ? lm : 3);    // clamp: rows 20-31 unused
            const int aoff1 = oc1 * 64 + lk * 16;
            const int n0 = wv * 32 + lm;
            const int n1 = n0 + 16;
            const int kyip = l >> 5, icb = (lk & 1) * 8;
            const unsigned short* Y2 = (const unsigned short*)&sm[OY2];
            const int b0 = ((n0 >> 3) + kyip) * 288 + (n0 & 7) * 24 + icb;
            const int b1 = ((n1 >> 3) + kyip) * 288 + (n1 & 7) * 24 + icb;
            #pragma unroll
            for (int p = 0; p < 3; ++p) {
                #pragma unroll
                for (int kx = 0; kx < 5; ++kx) {
                    const char* wa = W3 + (kx * 3 + p) * 1280;
                    bf16x8 A0 = *(const bf16x8*)(wa + aoff0);
                    bf16x8 A1 = *(const bf16x8*)(wa + aoff1);
                    const int bo = p * 576 + kx * 24;      // bf16 units
                    bf16x8 B0 = *(const bf16x8*)(Y2 + b0 + bo);
                    bf16x8 B1 = *(const bf16x8*)(Y2 + b1 + bo);
                    a00 = __builtin_amdgcn_mfma_f32_16x16x32_bf16(A0, B0, a00, 0, 0, 0);
                    a01 = __builtin_amdgcn_mfma_f32_16x16x32_bf16(A0, B1, a01, 0, 0, 0);
                    a10 = __builtin_amdgcn_mfma_f32_16x16x32_bf16(A1, B0, a10, 0, 0, 0);
                    a11 = __builtin_amdgcn_mfma_f32_16x16x32_bf16(A1, B1, a11, 0, 0, 0);
                }
            }
            float* C = &sm[OC2S];
            *(f32x4*)(C + n0 * 36 + lk * 4)      = a00;    // oc 0..15
            *(f32x4*)(C + n1 * 36 + lk * 4)      = a01;
            *(f32x4*)(C + n0 * 36 + 16 + lk * 4) = a10;    // oc 16..19 (+junk)
            *(f32x4*)(C + n1 * 36 + 16 + lk * 4) = a11;
        }
    }
    __syncthreads();

    // ---- pool C[64][36] + bias + relu -> p3[20,4,4] (80 threads) ----
    if (tid < 80) {
        int oc = tid % 20, py = tid / 20;      // py 0..3
        float b = conv2_b[oc];
        const float* C = &sm[OC2S];
        #pragma unroll
        for (int px = 0; px < 4; ++px) {
            int n00 = (2 * py) * 8 + 2 * px;
            float c00 = C[n00 * 36 + oc];
            float c01 = C[(n00 + 1) * 36 + oc];
            float c10 = C[(n00 + 8) * 36 + oc];
            float c11 = C[(n00 + 9) * 36 + oc];
            float m = fmaxf(fmaxf(c00, c01), fmaxf(c10, c11)) + b;
            sm[OP3 + oc * 16 + py * 4 + px] = fmaxf(m, 0.f);
        }
    }
    __syncthreads();

    // ---- fc 320->50, 2-way k-split (100 threads, 40 float4 each) ----
    if (tid < 100) {
        int g = tid / 50, o = tid % 50;
        const float4* wr4 = (const float4*)&fc1_w[o * 320 + g * 160];
        const float4* pp4 = (const float4*)&sm[OP3 + g * 160];
        float acc = 0.f;
        for (int i = 0; i < 40; ++i) {
            float4 wv = wr4[i], pv = pp4[i];
            acc = fmaf(wv.x, pv.x, acc);
            acc = fmaf(wv.y, pv.y, acc);
            acc = fmaf(wv.z, pv.z, acc);
            acc = fmaf(wv.w, pv.w, acc);
        }
        sm[OPF + tid] = acc;
    }
    __syncthreads();

    // ---- tail: wave 0, barrier-free (intra-wave LDS ordering) ----
    if (tid < 50) {
        float acc = fc1_b[tid] + sm[OPF + tid] + sm[OPF + 50 + tid];
        sm[OA1 + tid] = fmaxf(acc, 0.f);
    }
    if (tid < 10) {
        float acc = fc2_b[tid];
        const float2* wr = (const float2*)&fc2_w[tid * 50];
        #pragma unroll
        for (int i = 0; i < 25; ++i) {
            float2 wv = wr[i];
            acc = fmaf(wv.x, sm[OA1 + 2 * i], acc);
            acc = fmaf(wv.y, sm[OA1 + 2 * i + 1], acc);
        }
        sm[OZ + tid] = acc;
    }
    if (tid < 10) {
        float m = sm[OZ + 0];
        #pragma unroll
        for (int i = 1; i < 10; ++i) m = fmaxf(m, sm[OZ + i]);
        float s = 0.f;
        #pragma unroll
        for (int i = 0; i < 10; ++i) s += expf(sm[OZ + i] - m);
        out[n * 10 + tid] = sm[OZ + tid] - m - logf(s);
    }
}

extern "C" void kernel_launch(void* const* d_in, const int* in_sizes, int n_in,
                              void* d_out, int out_size, void* d_ws, size_t ws_size,
                              hipStream_t stream) {
    const float* x        = (const float*)d_in[0];
    const float* kf_w1    = (const float*)d_in[1];
    const float* kf_b1    = (const float*)d_in[2];
    const float* kf_w2    = (const float*)d_in[3];
    const float* kf_b2    = (const float*)d_in[4];
    const float* kf_fc1_w = (const float*)d_in[5];
    const float* kf_fc1_b = (const float*)d_in[6];
    const float* kf_fc2_w = (const float*)d_in[7];
    const float* kf_fc2_b = (const float*)d_in[8];
    const float* conv2_w  = (const float*)d_in[9];
    const float* conv2_b  = (const float*)d_in[10];
    const float* fc1_w    = (const float*)d_in[11];
    const float* fc1_b    = (const float*)d_in[12];
    const float* fc2_w    = (const float*)d_in[13];
    const float* fc2_b    = (const float*)d_in[14];

    const int N = in_sizes[0] / 784;   // 8192

    unsigned short* wsu = (unsigned short*)d_ws;   // 26368 B <= ws floor
    repack_w<<<(WSU_TOT + 255) / 256, 256, 0, stream>>>(conv2_w, kf_w2, wsu);

    fused_forward<<<N, TPB, 0, stream>>>(
        x, kf_w1, kf_b1, kf_w2, kf_b2, kf_fc1_w, kf_fc1_b, kf_fc2_w, kf_fc2_b,
        conv2_w, conv2_b, fc1_w, fc1_b, fc2_w, fc2_b, wsu, (float*)d_out);
}